// Round 19
// baseline (144.147 us; speedup 1.0000x reference)
//
#include <hip/hip_runtime.h>
#include <hip/hip_bf16.h>
#include <stdint.h>

// MahalanobisEnsembleLoss: out = sum_l w[l] * mean_n( v^T M_l v ),  v = F[l,n,:] - MEAN[l,idx[n],:]
// Decomposition (asymmetry-correct, R8-validated):  SY = 0.5*(M + M^T) in fp16
//   q_n = f^T SY f  -  f . GH[idx_n]  +  SS[idx_n]
//   GH[c] = 2*(SY . mean[c]) (fp16),  SS[c] = mean[c]^T SY mean[c] (fp32)
// R19: B-strip RESIDENT IN LDS (128 cols x 512 k = 128 KB, loaded once via
// global_load_lds from the rotation-baked SYT). K-loop has ZERO barriers and ZERO
// B-side global traffic; A-frags load global->reg->cvt directly (row-per-lane,
// depth-1 prefetch) so the F HBM stream is continuous instead of bursty --
// every prior round measured dur = FETCH/hbm_rate with rate ~0.9 TB/s (bursty).
#define LDIM 4
#define NDIM 16384
#define DDIM 512
#define CDIM 1000
#define NSTEP 16

// ---- workspace layout (bytes) ----
#define SYT_ELEMS ((size_t)LDIM * DDIM * DDIM)
#define GH_OFF   (SYT_ELEMS * 2)
#define GH_ELEMS ((size_t)LDIM * CDIM * DDIM)
#define SS_OFF   (GH_OFF + GH_ELEMS * 2)
#define SS_FLOATS ((size_t)LDIM * 1024)
#define WS_NEED  (SS_OFF + SS_FLOATS * 4)   // ~6.11 MiB

typedef __attribute__((ext_vector_type(8))) _Float16 f16x8;
typedef __attribute__((ext_vector_type(4))) float f32x4;

__device__ __forceinline__ unsigned short f2h(float x) {
  union { _Float16 h; unsigned short u; } c; c.h = (_Float16)x; return c.u;
}
__device__ __forceinline__ float h2f(unsigned short u) {
  union { unsigned short u; _Float16 h; } c; c.u = u; return (float)c.h;
}
__device__ __forceinline__ f16x8 cvt8(float4 a, float4 b) {
  f16x8 p;
  p[0] = (_Float16)a.x; p[1] = (_Float16)a.y; p[2] = (_Float16)a.z; p[3] = (_Float16)a.w;
  p[4] = (_Float16)b.x; p[5] = (_Float16)b.y; p[6] = (_Float16)b.z; p[7] = (_Float16)b.w;
  return p;
}
__device__ __forceinline__ void gload16(const void* g, void* l) {
  __builtin_amdgcn_global_load_lds(
      (const __attribute__((address_space(1))) void*)g,
      (__attribute__((address_space(3))) void*)l, 16, 0, 0);
}

// SYT element offset (halfwords) for (l, row d, k): tile s=k>>5, granule g=(k&31)>>3
// pre-rotated by (d>>1)&3; within-granule (k&7).   [verified R11-R18 end-to-end]
__device__ __forceinline__ size_t syt_off(int l, int d, int k) {
  return ((size_t)(l * NSTEP + (k >> 5)) * DDIM + d) * 32 +
         ((((k & 31) >> 3) + ((d >> 1) & 3)) & 3) * 8 + (k & 7);
}

// ---- main LDS: B-strip 16 steps x [128 rows][64 B] = 131072 | ids[256] | sval[256] | red
#define IDS_OFF 131072
#define SVAL_OFF 132096
#define RED_OFF 133120
#define LDS_MAIN 133152
#define LDS_PREP 65536

// K0: SYT = K-tiled, pre-swizzled fp16(0.5*(M+M^T)).
extern "C" __global__ void mel_mconv(const float* __restrict__ IC,
                                     unsigned short* __restrict__ SYT) {
  size_t i4 = (size_t)blockIdx.x * 256 + threadIdx.x;  // covers L*D*D/4
  size_t base = i4 * 4;
  int l = (int)(base >> 18);
  int rem = (int)(base & 262143);
  int d = rem >> 9;
  int e = rem & 511;
  float4 v = *(const float4*)(IC + base);
  const float* icl = IC + ((size_t)l << 18);
  float t0 = icl[(size_t)(e + 0) * DDIM + d];
  float t1 = icl[(size_t)(e + 1) * DDIM + d];
  float t2 = icl[(size_t)(e + 2) * DDIM + d];
  float t3 = icl[(size_t)(e + 3) * DDIM + d];
  *(ushort4*)(SYT + syt_off(l, d, e)) =
      make_ushort4(f2h(0.5f * (v.x + t0)), f2h(0.5f * (v.y + t1)),
                   f2h(0.5f * (v.z + t2)), f2h(0.5f * (v.w + t3)));
}

// K1: P = meanh . SY^T ; GH[c,:] = fp16(2P), SS[c] = meanh.P (validated, unchanged).
extern "C" __global__ __launch_bounds__(512, 2)
void mel_prep(const float* __restrict__ MEAN, const unsigned short* __restrict__ SYT,
              unsigned short* __restrict__ GH, float* __restrict__ SS) {
  extern __shared__ __align__(16) char lds[];
  const int t = threadIdx.x, lane = t & 63, w = t >> 6;
  const int l = blockIdx.x & 3, ct = blockIdx.x >> 2;
  const int row0 = ct * 64;
  const int col0 = w * 64, lrow = lane & 15, lkg = lane >> 4;
  const int lke = lkg << 3;

  {  // stage 64 mean rows as fp16 (rows >= CDIM -> 0); [64][512] XOR-granule layout
    const int srow = t >> 3;
    const int grow = row0 + srow;
    const float* mr = MEAN + ((size_t)l * CDIM + grow) * DDIM + ((t & 7) << 3);
    const int swb = srow * 1024 + (((t & 7) ^ (srow & 7)) << 4);
    const float4 z4 = {0.f, 0.f, 0.f, 0.f};
    for (int c = 0; c < 8; ++c) {
      float4 x = z4, y = z4;
      if (grow < CDIM) { x = *(const float4*)(mr + c * 64); y = *(const float4*)(mr + c * 64 + 4); }
      *(f16x8*)(lds + swb + c * 128) = cvt8(x, y);
    }
  }
  __syncthreads();

  f32x4 acc[4][4];
#pragma unroll
  for (int i = 0; i < 4; ++i)
#pragma unroll
    for (int j = 0; j < 4; ++j) acc[i][j] = {0.f, 0.f, 0.f, 0.f};

  for (int c = 0; c < 8; ++c) {
#pragma unroll
    for (int ks = 0; ks < 2; ++ks) {
      const int k = c * 64 + ks * 32 + lke;
      f16x8 b0 = *(const f16x8*)(SYT + syt_off(l, col0 + lrow, k));
      f16x8 b1 = *(const f16x8*)(SYT + syt_off(l, col0 + 16 + lrow, k));
      f16x8 b2 = *(const f16x8*)(SYT + syt_off(l, col0 + 32 + lrow, k));
      f16x8 b3 = *(const f16x8*)(SYT + syt_off(l, col0 + 48 + lrow, k));
      const int xo = c * 128 + ((((ks << 2) + lkg) ^ (lrow & 7)) << 4);
      f16x8 a0 = *(const f16x8*)(lds + lrow * 1024 + xo);
      f16x8 a1 = *(const f16x8*)(lds + (16 + lrow) * 1024 + xo);
      f16x8 a2 = *(const f16x8*)(lds + (32 + lrow) * 1024 + xo);
      f16x8 a3 = *(const f16x8*)(lds + (48 + lrow) * 1024 + xo);
#pragma unroll
      for (int nf = 0; nf < 4; ++nf) {
        f16x8 a = nf == 0 ? a0 : nf == 1 ? a1 : nf == 2 ? a2 : a3;
        acc[nf][0] = __builtin_amdgcn_mfma_f32_16x16x32_f16(a, b0, acc[nf][0], 0, 0, 0);
        acc[nf][1] = __builtin_amdgcn_mfma_f32_16x16x32_f16(a, b1, acc[nf][1], 0, 0, 0);
        acc[nf][2] = __builtin_amdgcn_mfma_f32_16x16x32_f16(a, b2, acc[nf][2], 0, 0, 0);
        acc[nf][3] = __builtin_amdgcn_mfma_f32_16x16x32_f16(a, b3, acc[nf][3], 0, 0, 0);
      }
    }
  }

#pragma unroll
  for (int nf = 0; nf < 4; ++nf)
#pragma unroll
    for (int r = 0; r < 4; ++r) {
      const int nloc = nf * 16 + lkg * 4 + r;
      const int grow = row0 + nloc;
      float sp = 0.f;
#pragma unroll
      for (int df = 0; df < 4; ++df) {
        const int dcol = col0 + df * 16 + lrow;
        const float av = acc[nf][df][r];  // P[c,d]
        const float mh = h2f(*(const unsigned short*)(
            lds + nloc * 1024 + (((dcol >> 3) ^ (nloc & 7)) << 4) + (dcol & 7) * 2));
        sp += mh * av;
        if (grow < CDIM) GH[((size_t)l * CDIM + grow) * DDIM + dcol] = f2h(2.f * av);
      }
      sp += __shfl_xor(sp, 1); sp += __shfl_xor(sp, 2);
      sp += __shfl_xor(sp, 4); sp += __shfl_xor(sp, 8);
      if (lrow == 0 && grow < CDIM) atomicAdd(SS + l * 1024 + grow, sp);
    }
}

// K2 main: SY 128-col strip resident in LDS (one gload pass); barrier-free N/K loop,
// A direct global->reg->cvt with depth-1 prefetch; wave = 32 rows x 128 cols.
extern "C" __global__ __launch_bounds__(512, 2)
void mel_main(const float* __restrict__ F, const float* __restrict__ W,
              const int* __restrict__ IDX, const unsigned short* __restrict__ SYT,
              const unsigned short* __restrict__ GH, const float* __restrict__ SS,
              float* __restrict__ OUT) {
  extern __shared__ __align__(16) char lds[];
  int* ids = (int*)(lds + IDS_OFF);
  float* sval = (float*)(lds + SVAL_OFF);
  float* red = (float*)(lds + RED_OFF);
  const int t = threadIdx.x, lane = t & 63, w = t >> 6;  // 8 waves
  const int bid = blockIdx.x, xcd = bid & 7, l = xcd >> 1;
  const int blkl = (bid >> 3) + ((xcd & 1) << 7);  // 0..255 within l
  const int strip = blkl & 3;
  const int n0 = (blkl >> 2) * 256;
  const int c0 = strip * 128;
  const int lrow = lane & 15, lkg = lane >> 4;
  const int wbase = w * 32;  // wave's 32 rows

  // ---- stage B-strip into LDS: 16 steps x 8KB, SYT slice is byte-contiguous
  // (rotation baked in; linear copy, R11-validated copy/read pair).
  const unsigned short* syt_strip =
      SYT + (size_t)l * NSTEP * DDIM * 32 + (size_t)c0 * 32;
#pragma unroll
  for (int s = 0; s < NSTEP; ++s)
    gload16(syt_strip + (size_t)s * DDIM * 32 + t * 8,
            lds + s * 8192 + ((t & ~63) << 4));
  if (t < 256) {
    const int cc = IDX[n0 + t];
    ids[t] = cc;
    sval[t] = SS[l * 1024 + cc];
  }
  __syncthreads();  // only barrier before the final reduction

  f32x4 acc[2][8];  // [row frag][col frag]
#pragma unroll
  for (int i = 0; i < 2; ++i)
#pragma unroll
    for (int j = 0; j < 8; ++j) acc[i][j] = {0.f, 0.f, 0.f, 0.f};

  // ---- barrier-free K-loop: A direct from F (depth-1 prefetch), B from LDS.
  const float* fr0 = F + ((size_t)l * NDIM + n0 + wbase + lrow) * DDIM;
  const float* fr1 = fr0 + 16 * DDIM;
  const int k0 = lkg * 8;
  float4 p00 = *(const float4*)(fr0 + k0);
  float4 p01 = *(const float4*)(fr0 + k0 + 4);
  float4 p10 = *(const float4*)(fr1 + k0);
  float4 p11 = *(const float4*)(fr1 + k0 + 4);
#pragma unroll
  for (int s = 0; s < NSTEP; ++s) {
    float4 c00 = p00, c01 = p01, c10 = p10, c11 = p11;
    if (s + 1 < NSTEP) {
      const int k1 = (s + 1) * 32 + k0;
      p00 = *(const float4*)(fr0 + k1);
      p01 = *(const float4*)(fr0 + k1 + 4);
      p10 = *(const float4*)(fr1 + k1);
      p11 = *(const float4*)(fr1 + k1 + 4);
    }
    f16x8 af0 = cvt8(c00, c01);
    f16x8 af1 = cvt8(c10, c11);
    const char* bs = lds + s * 8192;
#pragma unroll
    for (int df = 0; df < 8; ++df) {
      const int dl = df * 16 + lrow;
      f16x8 bf = *(const f16x8*)(bs + dl * 64 +
                                 (((lkg + ((dl >> 1) & 3)) & 3) << 4));
      acc[0][df] = __builtin_amdgcn_mfma_f32_16x16x32_f16(af0, bf, acc[0][df], 0, 0, 0);
      acc[1][df] = __builtin_amdgcn_mfma_f32_16x16x32_f16(af1, bf, acc[1][df], 0, 0, 0);
    }
  }

  // ---- epilogue: q-partial = sum_d fh*(W[n,d] - GH[c,d]); fh from F (L3-resident).
  const unsigned short* gh_l = GH + (size_t)l * CDIM * DDIM;
  const float* fre = F + ((size_t)l * NDIM + n0) * DDIM;
  float tsum = 0.f;
#pragma unroll
  for (int nf = 0; nf < 2; ++nf)
#pragma unroll
    for (int df = 0; df < 8; ++df) {
      const int col = c0 + df * 16 + lrow;
      f32x4 cfrag = acc[nf][df];
#pragma unroll
      for (int r = 0; r < 4; ++r) {
        const int rowl = wbase + nf * 16 + lkg * 4 + r;
        const float fh = fre[(size_t)rowl * DDIM + col];
        const float gh = h2f(gh_l[(size_t)ids[rowl] * DDIM + col]);
        tsum += fh * (cfrag[r] - gh);
        if (strip == 0 && df == 0 && lrow == 0) tsum += sval[rowl];
      }
    }
#pragma unroll
  for (int off = 32; off > 0; off >>= 1) tsum += __shfl_down(tsum, off);
  __syncthreads();
  if (lane == 0) red[w] = tsum;
  __syncthreads();
  if (t == 0) {
    float ssum = 0.f;
#pragma unroll
    for (int i = 0; i < 8; ++i) ssum += red[i];
    atomicAdd(OUT, ssum * (W[l] / (float)NDIM));
  }
}

// Correct-but-slow fp32 fallback (only if ws_size < WS_NEED).
extern "C" __global__ void mel_fallback(const float* __restrict__ F,
                                        const float* __restrict__ MEAN,
                                        const float* __restrict__ IC,
                                        const float* __restrict__ W,
                                        const int* __restrict__ IDX,
                                        float* __restrict__ OUT) {
  __shared__ float v[8][DDIM];
  __shared__ float red[256];
  const int t = threadIdx.x;
  const int l = blockIdx.y;
  const int n0 = blockIdx.x * 8;
  for (int i = t; i < 8 * DDIM; i += 256) {
    int n = i >> 9, e = i & 511;
    int c = IDX[n0 + n];
    v[n][e] = F[((size_t)l * NDIM + n0 + n) * DDIM + e] -
              MEAN[((size_t)l * CDIM + c) * DDIM + e];
  }
  __syncthreads();
  const float* icl = IC + ((size_t)l << 18);
  float part = 0.f;
  for (int rep = 0; rep < 2; ++rep) {
    int d = t + rep * 256;
    float s[8];
#pragma unroll
    for (int j = 0; j < 8; ++j) s[j] = 0.f;
    for (int e = 0; e < DDIM; ++e) {
      float m = icl[(size_t)d * DDIM + e];
#pragma unroll
      for (int j = 0; j < 8; ++j) s[j] += m * v[j][e];
    }
#pragma unroll
    for (int j = 0; j < 8; ++j) part += v[j][d] * s[j];
  }
  red[t] = part;
  __syncthreads();
  for (int o = 128; o > 0; o >>= 1) {
    if (t < o) red[t] += red[t + o];
    __syncthreads();
  }
  if (t == 0) atomicAdd(OUT, red[0] * (W[l] / (float)NDIM));
}

extern "C" void kernel_launch(void* const* d_in, const int* in_sizes, int n_in,
                              void* d_out, int out_size, void* d_ws, size_t ws_size,
                              hipStream_t stream) {
  const float* F = (const float*)d_in[0];
  const float* MEAN = (const float*)d_in[1];
  const float* IC = (const float*)d_in[2];
  const float* W = (const float*)d_in[3];
  const int* IDX = (const int*)d_in[4];
  float* OUT = (float*)d_out;

  hipMemsetAsync(d_out, 0, sizeof(float) * (size_t)out_size, stream);

  if (ws_size >= WS_NEED) {
    unsigned short* SYTp = (unsigned short*)d_ws;
    unsigned short* GHp = (unsigned short*)((char*)d_ws + GH_OFF);
    float* SSp = (float*)((char*)d_ws + SS_OFF);
    hipMemsetAsync(SSp, 0, SS_FLOATS * 4, stream);
    mel_mconv<<<dim3(1024), dim3(256), 0, stream>>>(IC, SYTp);
    (void)hipFuncSetAttribute(reinterpret_cast<const void*>(mel_prep),
                              hipFuncAttributeMaxDynamicSharedMemorySize, LDS_PREP);
    mel_prep<<<dim3(64), dim3(512), LDS_PREP, stream>>>(MEAN, SYTp, GHp, SSp);
    (void)hipFuncSetAttribute(reinterpret_cast<const void*>(mel_main),
                              hipFuncAttributeMaxDynamicSharedMemorySize, LDS_MAIN);
    mel_main<<<dim3(1024), dim3(512), LDS_MAIN, stream>>>(
        F, W, IDX, SYTp, GHp, SSp, OUT);
  } else {
    mel_fallback<<<dim3(NDIM / 8, LDIM), dim3(256), 0, stream>>>(F, MEAN, IC, W, IDX, OUT);
  }
}

// Round 20
// 87.264 us; speedup vs baseline: 1.6518x; 1.6518x over previous
//
#include <hip/hip_runtime.h>
#include <hip/hip_bf16.h>
#include <stdint.h>

// MahalanobisEnsembleLoss: out = sum_l w[l] * mean_n( v^T M_l v ),  v = F[l,n,:] - MEAN[l,idx[n],:]
// Decomposition (asymmetry-correct, R8-validated):  SY = 0.5*(M + M^T) in fp16
//   q_n = f^T SY f  -  f . GH[idx_n]  +  SS[idx_n]
//   GH[c] = 2*(SY . mean[c]) (fp16),  SS[c] = mean[c]^T SY mean[c] (fp32)
// R20 = R13 (87.8us champion) + cross-barrier B-prefetch: first sub-step's 4 B-frags
// (bq) issued BEFORE the quarter barrier; barrier is lgkmcnt(0)-only (raw s_barrier,
// m201 pattern) so bq stays in flight across it -- removes the per-quarter cold
// restart of the B-latency chain that __syncthreads' vmcnt(0) drain forced.
#define LDIM 4
#define NDIM 16384
#define DDIM 512
#define CDIM 1000
#define NSTEP 16

// ---- workspace layout (bytes) ----
#define SYT_ELEMS ((size_t)LDIM * DDIM * DDIM)
#define GH_OFF   (SYT_ELEMS * 2)
#define GH_ELEMS ((size_t)LDIM * CDIM * DDIM)
#define SS_OFF   (GH_OFF + GH_ELEMS * 2)
#define SS_FLOATS ((size_t)LDIM * 1024)
#define WS_NEED  (SS_OFF + SS_FLOATS * 4)   // ~6.11 MiB

typedef __attribute__((ext_vector_type(8))) _Float16 f16x8;
typedef __attribute__((ext_vector_type(4))) float f32x4;

__device__ __forceinline__ unsigned short f2h(float x) {
  union { _Float16 h; unsigned short u; } c; c.h = (_Float16)x; return c.u;
}
__device__ __forceinline__ float h2f(unsigned short u) {
  union { unsigned short u; _Float16 h; } c; c.u = u; return (float)c.h;
}
__device__ __forceinline__ f16x8 cvt8(float4 a, float4 b) {
  f16x8 p;
  p[0] = (_Float16)a.x; p[1] = (_Float16)a.y; p[2] = (_Float16)a.z; p[3] = (_Float16)a.w;
  p[4] = (_Float16)b.x; p[5] = (_Float16)b.y; p[6] = (_Float16)b.z; p[7] = (_Float16)b.w;
  return p;
}

// SYT element offset (halfwords) for (l, row d, k): tile s=k>>5, granule g=(k&31)>>3
// pre-rotated by (d>>1)&3; within-granule (k&7).   [verified R11-R19 end-to-end]
__device__ __forceinline__ size_t syt_off(int l, int d, int k) {
  return ((size_t)(l * NSTEP + (k >> 5)) * DDIM + d) * 32 +
         ((((k & 31) >> 3) + ((d >> 1) & 3)) & 3) * 8 + (k & 7);
}

// lgkmcnt(0)-only barrier: ds ops drained, global register-loads stay in flight.
__device__ __forceinline__ void barrier_lgkm_only() {
  asm volatile("s_waitcnt lgkmcnt(0)" ::: "memory");
  __builtin_amdgcn_s_barrier();
  __builtin_amdgcn_sched_barrier(0);
}

// ---- main LDS: A image 16 chunks x [64 rows][32 e] (rot-granule swizzled) | tables
#define IDS_OFF 65536
#define SVAL_OFF 65792
#define RED_OFF 66048
#define LDS_MAIN 66080
#define LDS_PREP 65536

// K0: SYT = K-tiled, pre-swizzled fp16(0.5*(M+M^T)).
extern "C" __global__ void mel_mconv(const float* __restrict__ IC,
                                     unsigned short* __restrict__ SYT) {
  size_t i4 = (size_t)blockIdx.x * 256 + threadIdx.x;  // covers L*D*D/4
  size_t base = i4 * 4;
  int l = (int)(base >> 18);
  int rem = (int)(base & 262143);
  int d = rem >> 9;
  int e = rem & 511;
  float4 v = *(const float4*)(IC + base);
  const float* icl = IC + ((size_t)l << 18);
  float t0 = icl[(size_t)(e + 0) * DDIM + d];
  float t1 = icl[(size_t)(e + 1) * DDIM + d];
  float t2 = icl[(size_t)(e + 2) * DDIM + d];
  float t3 = icl[(size_t)(e + 3) * DDIM + d];
  *(ushort4*)(SYT + syt_off(l, d, e)) =
      make_ushort4(f2h(0.5f * (v.x + t0)), f2h(0.5f * (v.y + t1)),
                   f2h(0.5f * (v.z + t2)), f2h(0.5f * (v.w + t3)));
}

// K1: P = meanh . SY^T ; GH[c,:] = fp16(2P), SS[c] = meanh.P (validated, unchanged).
extern "C" __global__ __launch_bounds__(512, 2)
void mel_prep(const float* __restrict__ MEAN, const unsigned short* __restrict__ SYT,
              unsigned short* __restrict__ GH, float* __restrict__ SS) {
  extern __shared__ __align__(16) char lds[];
  const int t = threadIdx.x, lane = t & 63, w = t >> 6;
  const int l = blockIdx.x & 3, ct = blockIdx.x >> 2;
  const int row0 = ct * 64;
  const int col0 = w * 64, lrow = lane & 15, lkg = lane >> 4;
  const int lke = lkg << 3;

  {  // stage 64 mean rows as fp16 (rows >= CDIM -> 0); [64][512] XOR-granule layout
    const int srow = t >> 3;
    const int grow = row0 + srow;
    const float* mr = MEAN + ((size_t)l * CDIM + grow) * DDIM + ((t & 7) << 3);
    const int swb = srow * 1024 + (((t & 7) ^ (srow & 7)) << 4);
    const float4 z4 = {0.f, 0.f, 0.f, 0.f};
    for (int c = 0; c < 8; ++c) {
      float4 x = z4, y = z4;
      if (grow < CDIM) { x = *(const float4*)(mr + c * 64); y = *(const float4*)(mr + c * 64 + 4); }
      *(f16x8*)(lds + swb + c * 128) = cvt8(x, y);
    }
  }
  __syncthreads();

  f32x4 acc[4][4];
#pragma unroll
  for (int i = 0; i < 4; ++i)
#pragma unroll
    for (int j = 0; j < 4; ++j) acc[i][j] = {0.f, 0.f, 0.f, 0.f};

  for (int c = 0; c < 8; ++c) {
#pragma unroll
    for (int ks = 0; ks < 2; ++ks) {
      const int k = c * 64 + ks * 32 + lke;
      f16x8 b0 = *(const f16x8*)(SYT + syt_off(l, col0 + lrow, k));
      f16x8 b1 = *(const f16x8*)(SYT + syt_off(l, col0 + 16 + lrow, k));
      f16x8 b2 = *(const f16x8*)(SYT + syt_off(l, col0 + 32 + lrow, k));
      f16x8 b3 = *(const f16x8*)(SYT + syt_off(l, col0 + 48 + lrow, k));
      const int xo = c * 128 + ((((ks << 2) + lkg) ^ (lrow & 7)) << 4);
      f16x8 a0 = *(const f16x8*)(lds + lrow * 1024 + xo);
      f16x8 a1 = *(const f16x8*)(lds + (16 + lrow) * 1024 + xo);
      f16x8 a2 = *(const f16x8*)(lds + (32 + lrow) * 1024 + xo);
      f16x8 a3 = *(const f16x8*)(lds + (48 + lrow) * 1024 + xo);
#pragma unroll
      for (int nf = 0; nf < 4; ++nf) {
        f16x8 a = nf == 0 ? a0 : nf == 1 ? a1 : nf == 2 ? a2 : a3;
        acc[nf][0] = __builtin_amdgcn_mfma_f32_16x16x32_f16(a, b0, acc[nf][0], 0, 0, 0);
        acc[nf][1] = __builtin_amdgcn_mfma_f32_16x16x32_f16(a, b1, acc[nf][1], 0, 0, 0);
        acc[nf][2] = __builtin_amdgcn_mfma_f32_16x16x32_f16(a, b2, acc[nf][2], 0, 0, 0);
        acc[nf][3] = __builtin_amdgcn_mfma_f32_16x16x32_f16(a, b3, acc[nf][3], 0, 0, 0);
      }
    }
  }

#pragma unroll
  for (int nf = 0; nf < 4; ++nf)
#pragma unroll
    for (int r = 0; r < 4; ++r) {
      const int nloc = nf * 16 + lkg * 4 + r;
      const int grow = row0 + nloc;
      float sp = 0.f;
#pragma unroll
      for (int df = 0; df < 4; ++df) {
        const int dcol = col0 + df * 16 + lrow;
        const float av = acc[nf][df][r];  // P[c,d]
        const float mh = h2f(*(const unsigned short*)(
            lds + nloc * 1024 + (((dcol >> 3) ^ (nloc & 7)) << 4) + (dcol & 7) * 2));
        sp += mh * av;
        if (grow < CDIM) GH[((size_t)l * CDIM + grow) * DDIM + dcol] = f2h(2.f * av);
      }
      sp += __shfl_xor(sp, 1); sp += __shfl_xor(sp, 2);
      sp += __shfl_xor(sp, 4); sp += __shfl_xor(sp, 8);
      if (lrow == 0 && grow < CDIM) atomicAdd(SS + l * 1024 + grow, sp);
    }
}

// K2 main: R13 quarter-pipelined A staging + cross-barrier B-prefetch (bq);
// B direct from SYT (L2); epilogue fh from the LDS A-image. 512 thr / 8 waves.
extern "C" __global__ __launch_bounds__(512, 4)
void mel_main(const float* __restrict__ F, const float* __restrict__ W,
              const int* __restrict__ IDX, const unsigned short* __restrict__ SYT,
              const unsigned short* __restrict__ GH, const float* __restrict__ SS,
              float* __restrict__ OUT) {
  extern __shared__ __align__(16) char lds[];
  int* ids = (int*)(lds + IDS_OFF);
  float* sval = (float*)(lds + SVAL_OFF);
  float* red = (float*)(lds + RED_OFF);
  const int t = threadIdx.x, lane = t & 63, w = t >> 6;  // 8 waves
  const int bid = blockIdx.x, xcd = bid & 7, l = xcd >> 1;
  const int bx = ((bid >> 3) << 1) | (xcd & 1);  // 0..255 within l
  const int n0 = bx * 64;
  const int col0 = w * 64;                        // wave's 64 cols
  const int lrow = lane & 15, lkg = lane >> 4;

  if (t < 64) {
    const int cc = IDX[n0 + t];
    ids[t] = cc;
    sval[t] = SS[l * 1024 + cc];
  }

  // A staging coords: row t>>3, e-quad (t&7)*4 within each 32-wide chunk
  const int a_row = t >> 3, a_el = (t & 7) << 2;
  const float* fA = F + ((size_t)l * NDIM + n0 + a_row) * DDIM + a_el;
  const int a_wb = a_row * 64 + ((((a_el >> 3) + ((a_row >> 1) & 3)) & 3) << 4) +
                   ((a_el & 7) << 1);

  // cross-barrier B-prefetch registers (first sub-step of next quarter)
  f16x8 bq[4];
#pragma unroll
  for (int df = 0; df < 4; ++df)
    bq[df] = *(const f16x8*)(SYT + syt_off(l, col0 + df * 16 + lrow, lkg * 8));

  {  // prologue: quarter 0 (chunks 0-3)
    float4 x0 = *(const float4*)(fA);
    float4 x1 = *(const float4*)(fA + 32);
    float4 x2 = *(const float4*)(fA + 64);
    float4 x3 = *(const float4*)(fA + 96);
    *(ushort4*)(lds + 0 * 4096 + a_wb) = make_ushort4(f2h(x0.x), f2h(x0.y), f2h(x0.z), f2h(x0.w));
    *(ushort4*)(lds + 1 * 4096 + a_wb) = make_ushort4(f2h(x1.x), f2h(x1.y), f2h(x1.z), f2h(x1.w));
    *(ushort4*)(lds + 2 * 4096 + a_wb) = make_ushort4(f2h(x2.x), f2h(x2.y), f2h(x2.z), f2h(x2.w));
    *(ushort4*)(lds + 3 * 4096 + a_wb) = make_ushort4(f2h(x3.x), f2h(x3.y), f2h(x3.z), f2h(x3.w));
  }
  barrier_lgkm_only();  // bq stays in flight across the barrier

  f32x4 acc[4][4];  // [nf rows][df cols]
#pragma unroll
  for (int i = 0; i < 4; ++i)
#pragma unroll
    for (int j = 0; j < 4; ++j) acc[i][j] = {0.f, 0.f, 0.f, 0.f};

  // ---- quarter-pipelined K-loop: load quarter q+1 early, compute quarter q,
  //      write quarter q+1 + issue bq for next quarter BEFORE the barrier.
#pragma unroll
  for (int q = 0; q < 4; ++q) {
    float4 n0v, n1v, n2v, n3v;
    if (q < 3) {  // issue next quarter's F loads (consumed after compute)
      const float* fn = fA + (q + 1) * 128;
      n0v = *(const float4*)(fn);
      n1v = *(const float4*)(fn + 32);
      n2v = *(const float4*)(fn + 64);
      n3v = *(const float4*)(fn + 96);
    }
#pragma unroll
    for (int s4 = 0; s4 < 4; ++s4) {
      const int s = q * 4 + s4;
      f16x8 bf[4], af[4];
      if (s4 == 0) {
#pragma unroll
        for (int df = 0; df < 4; ++df) bf[df] = bq[df];
      } else {
#pragma unroll
        for (int df = 0; df < 4; ++df)
          bf[df] = *(const f16x8*)(SYT + syt_off(l, col0 + df * 16 + lrow, s * 32 + lkg * 8));
      }
#pragma unroll
      for (int nf = 0; nf < 4; ++nf) {
        const int row = nf * 16 + lrow;
        af[nf] = *(const f16x8*)(lds + s * 4096 + row * 64 +
                                 (((lkg + ((row >> 1) & 3)) & 3) << 4));
      }
#pragma unroll
      for (int nf = 0; nf < 4; ++nf)
#pragma unroll
        for (int df = 0; df < 4; ++df)
          acc[nf][df] = __builtin_amdgcn_mfma_f32_16x16x32_f16(af[nf], bf[df], acc[nf][df], 0, 0, 0);
    }
    if (q < 3) {
      // issue next quarter's first-sub-step B-frags FIRST (max latency coverage)
#pragma unroll
      for (int df = 0; df < 4; ++df)
        bq[df] = *(const f16x8*)(SYT + syt_off(l, col0 + df * 16 + lrow,
                                               (q + 1) * 128 + lkg * 8));
      char* base = lds + (q + 1) * 16384;
      *(ushort4*)(base + 0 * 4096 + a_wb) = make_ushort4(f2h(n0v.x), f2h(n0v.y), f2h(n0v.z), f2h(n0v.w));
      *(ushort4*)(base + 1 * 4096 + a_wb) = make_ushort4(f2h(n1v.x), f2h(n1v.y), f2h(n1v.z), f2h(n1v.w));
      *(ushort4*)(base + 2 * 4096 + a_wb) = make_ushort4(f2h(n2v.x), f2h(n2v.y), f2h(n2v.z), f2h(n2v.w));
      *(ushort4*)(base + 3 * 4096 + a_wb) = make_ushort4(f2h(n3v.x), f2h(n3v.y), f2h(n3v.z), f2h(n3v.w));
      barrier_lgkm_only();  // ds_writes visible; bq loads remain in flight
    }
  }

  // ---- epilogue: q-partial = sum_d fh*(W[n,d] - GH[c,d]); fh from LDS A-image.
  const unsigned short* gh_l = GH + (size_t)l * CDIM * DDIM;
  float tsum = 0.f;
#pragma unroll
  for (int nf = 0; nf < 4; ++nf)
#pragma unroll
    for (int df = 0; df < 4; ++df) {
      const int col = col0 + df * 16 + lrow;
      f32x4 cfrag = acc[nf][df];
#pragma unroll
      for (int r = 0; r < 4; ++r) {
        const int rowl = nf * 16 + lkg * 4 + r;
        const float fh = h2f(*(const unsigned short*)(
            lds + (col >> 5) * 4096 + rowl * 64 +
            (((((col & 31) >> 3) + ((rowl >> 1) & 3)) & 3) << 4) + ((col & 7) << 1)));
        const float gh = h2f(gh_l[(size_t)ids[rowl] * DDIM + col]);
        tsum += fh * (cfrag[r] - gh);
        if (w == 0 && df == 0 && lrow == 0) tsum += sval[rowl];
      }
    }
#pragma unroll
  for (int off = 32; off > 0; off >>= 1) tsum += __shfl_down(tsum, off);
  __syncthreads();
  if (lane == 0) red[w] = tsum;
  __syncthreads();
  if (t == 0) {
    float ssum = 0.f;
#pragma unroll
    for (int i = 0; i < 8; ++i) ssum += red[i];
    atomicAdd(OUT, ssum * (W[l] / (float)NDIM));
  }
}

// Correct-but-slow fp32 fallback (only if ws_size < WS_NEED).
extern "C" __global__ void mel_fallback(const float* __restrict__ F,
                                        const float* __restrict__ MEAN,
                                        const float* __restrict__ IC,
                                        const float* __restrict__ W,
                                        const int* __restrict__ IDX,
                                        float* __restrict__ OUT) {
  __shared__ float v[8][DDIM];
  __shared__ float red[256];
  const int t = threadIdx.x;
  const int l = blockIdx.y;
  const int n0 = blockIdx.x * 8;
  for (int i = t; i < 8 * DDIM; i += 256) {
    int n = i >> 9, e = i & 511;
    int c = IDX[n0 + n];
    v[n][e] = F[((size_t)l * NDIM + n0 + n) * DDIM + e] -
              MEAN[((size_t)l * CDIM + c) * DDIM + e];
  }
  __syncthreads();
  const float* icl = IC + ((size_t)l << 18);
  float part = 0.f;
  for (int rep = 0; rep < 2; ++rep) {
    int d = t + rep * 256;
    float s[8];
#pragma unroll
    for (int j = 0; j < 8; ++j) s[j] = 0.f;
    for (int e = 0; e < DDIM; ++e) {
      float m = icl[(size_t)d * DDIM + e];
#pragma unroll
      for (int j = 0; j < 8; ++j) s[j] += m * v[j][e];
    }
#pragma unroll
    for (int j = 0; j < 8; ++j) part += v[j][d] * s[j];
  }
  red[t] = part;
  __syncthreads();
  for (int o = 128; o > 0; o >>= 1) {
    if (t < o) red[t] += red[t + o];
    __syncthreads();
  }
  if (t == 0) atomicAdd(OUT, red[0] * (W[l] / (float)NDIM));
}

extern "C" void kernel_launch(void* const* d_in, const int* in_sizes, int n_in,
                              void* d_out, int out_size, void* d_ws, size_t ws_size,
                              hipStream_t stream) {
  const float* F = (const float*)d_in[0];
  const float* MEAN = (const float*)d_in[1];
  const float* IC = (const float*)d_in[2];
  const float* W = (const float*)d_in[3];
  const int* IDX = (const int*)d_in[4];
  float* OUT = (float*)d_out;

  hipMemsetAsync(d_out, 0, sizeof(float) * (size_t)out_size, stream);

  if (ws_size >= WS_NEED) {
    unsigned short* SYTp = (unsigned short*)d_ws;
    unsigned short* GHp = (unsigned short*)((char*)d_ws + GH_OFF);
    float* SSp = (float*)((char*)d_ws + SS_OFF);
    hipMemsetAsync(SSp, 0, SS_FLOATS * 4, stream);
    mel_mconv<<<dim3(1024), dim3(256), 0, stream>>>(IC, SYTp);
    (void)hipFuncSetAttribute(reinterpret_cast<const void*>(mel_prep),
                              hipFuncAttributeMaxDynamicSharedMemorySize, LDS_PREP);
    mel_prep<<<dim3(64), dim3(512), LDS_PREP, stream>>>(MEAN, SYTp, GHp, SSp);
    (void)hipFuncSetAttribute(reinterpret_cast<const void*>(mel_main),
                              hipFuncAttributeMaxDynamicSharedMemorySize, LDS_MAIN);
    mel_main<<<dim3(1024), dim3(512), LDS_MAIN, stream>>>(
        F, W, IDX, SYTp, GHp, SSp, OUT);
  } else {
    mel_fallback<<<dim3(NDIM / 8, LDIM), dim3(256), 0, stream>>>(F, MEAN, IC, W, IDX, OUT);
  }
}